// Round 15
// baseline (415.650 us; speedup 1.0000x reference)
//
#include <hip/hip_runtime.h>
#include <hip/hip_bf16.h>
#include <stdint.h>

#define DEV __device__ __forceinline__

typedef __bf16 bf16x8 __attribute__((ext_vector_type(8)));
typedef float f32x4 __attribute__((ext_vector_type(4)));
typedef unsigned short ushort8_t __attribute__((ext_vector_type(8)));
typedef unsigned short ushort4_t __attribute__((ext_vector_type(4)));

constexpr int S = 2048;
constexpr int D = 4096;
constexpr int H = 32;
constexpr int HD = 128;
constexpr float kSc = 0.08838834764831845f * 1.4426950408889634f;  // 1/sqrt(HD) * log2(e)

DEV unsigned short f2bf(float f) {
    uint32_t u = __builtin_bit_cast(uint32_t, f);
    u += 0x7fffu + ((u >> 16) & 1u);
    return (unsigned short)(u >> 16);
}
DEV float bf2f(unsigned short h) {
    uint32_t u = ((uint32_t)h) << 16;
    return __builtin_bit_cast(float, u);
}

DEV void gload_lds16(const void* g, void* l) {
    __builtin_amdgcn_global_load_lds(
        (const __attribute__((address_space(1))) void*)g,
        (__attribute__((address_space(3))) void*)l,
        16, 0, 0);
}

DEV f32x4 mfma16(bf16x8 a, bf16x8 b, f32x4 c) {
    return __builtin_amdgcn_mfma_f32_16x16x32_bf16(a, b, c, 0, 0, 0);
}

// ---------------- fp32 -> bf16 convert, all 5 tensors in one dispatch -------
__global__ __launch_bounds__(256) void cvt_all(const float* __restrict__ hs,
                                               const float* __restrict__ w0,
                                               const float* __restrict__ w1,
                                               const float* __restrict__ w2,
                                               const float* __restrict__ w3,
                                               unsigned short* __restrict__ hsb,
                                               unsigned short* __restrict__ o0,
                                               unsigned short* __restrict__ o1,
                                               unsigned short* __restrict__ o2,
                                               unsigned short* __restrict__ o3) {
    const int b = blockIdx.x;
    const float* in;
    unsigned short* out;
    size_t blk;
    if (b < 4096) {
        in = hs; out = hsb; blk = (size_t)b;
    } else {
        const int i = b - 4096;
        const int w = i >> 13;
        const int r = i & 8191;
        in  = (w == 0) ? w0 : (w == 1) ? w1 : (w == 2) ? w2 : w3;
        out = (w == 0) ? o0 : (w == 1) ? o1 : (w == 2) ? o2 : o3;
        blk = (size_t)r;
    }
    const size_t i8 = blk * 256 + threadIdx.x;
    f32x4 a = ((const f32x4*)in)[2 * i8];
    f32x4 c = ((const f32x4*)in)[2 * i8 + 1];
    ushort8_t o;
    o[0] = f2bf(a[0]); o[1] = f2bf(a[1]); o[2] = f2bf(a[2]); o[3] = f2bf(a[3]);
    o[4] = f2bf(c[0]); o[5] = f2bf(c[1]); o[6] = f2bf(c[2]); o[7] = f2bf(c[3]);
    ((ushort8_t*)out)[i8] = o;
}

// ---------------- QKV GEMM: 256x192, 8-phase, depth-8 A-prefetch (R14) ------
__global__ __launch_bounds__(512, 2) void gemm_qkv8d(const unsigned short* __restrict__ Ap,
                                                     const unsigned short* __restrict__ Bp,
                                                     unsigned short* __restrict__ Oq,
                                                     unsigned short* __restrict__ Ok,
                                                     unsigned short* __restrict__ Ovt) {
    constexpr int NT = 3;
    extern __shared__ unsigned short lds8[];

    const int tix = threadIdx.x;
    const int lane = tix & 63;
    const int w = tix >> 6;
    const int g = lane >> 4;
    const int rl = lane & 15;
    const int wm = w >> 2;
    const int wn = w & 3;
    const int bc0 = wn * 48;
    const int rx = rl & 7;

    const int yy = blockIdx.x & 7;
    const int xx = blockIdx.x >> 3;
    const int m0 = yy * 256;
    const int n0 = xx * 192;

    int srowA[2], scolA[2];
#pragma unroll
    for (int u = 0; u < 2; ++u) {
        const int c = u * 512 + tix;
        srowA[u] = c >> 3;
        scolA[u] = ((c & 7) ^ (srowA[u] & 7)) << 3;
    }
    int srowB[3], scolB[3];
#pragma unroll
    for (int u = 0; u < 3; ++u) {
        const int c = u * 512 + tix;
        srowB[u] = c >> 3;
        scolB[u] = ((c & 7) ^ (srowB[u] & 7)) << 3;
    }

    f32x4 acc[4][2][NT] = {};
    bf16x8 bfr[NT][2];

#define STG_A(t, h)                                                               \
    if ((t) < 64) {                                                               \
        unsigned short* as_ = lds8 + (((t) % 3) * 2 + (h)) * 8192;                \
        _Pragma("unroll") for (int u = 0; u < 2; ++u)                             \
            gload_lds16(Ap + (size_t)(m0 + (h) * 128 + srowA[u]) * 4096 +         \
                            (t) * 64 + scolA[u],                                  \
                        &as_[(u * 512 + tix) * 8]);                               \
    }
#define STG_B(t)                                                                  \
    if ((t) < 64) {                                                               \
        unsigned short* bs_ = lds8 + 49152 + ((t) & 1) * 12288;                   \
        _Pragma("unroll") for (int u = 0; u < 3; ++u)                             \
            gload_lds16(Bp + (size_t)(n0 + srowB[u]) * 4096 +                     \
                            (t) * 64 + scolB[u],                                  \
                        &bs_[(u * 512 + tix) * 8]);                               \
    }

#define PH(pp, bb, q, STG, VM)                                                    \
    {                                                                             \
        const char* aB = (const char*)(lds8 + ((pp) * 2 + wm) * 8192);            \
        const char* bB = (const char*)(lds8 + 49152 + (bb) * 12288);              \
        bf16x8 af[2][2];                                                          \
        _Pragma("unroll") for (int mi = 0; mi < 2; ++mi)                          \
        _Pragma("unroll") for (int ks = 0; ks < 2; ++ks) {                        \
            const int ab = ((q) * 32 + mi * 16 + rl) * 128 +                      \
                           ((((ks << 2) + g) ^ rx) << 4);                         \
            af[mi][ks] = *(const bf16x8*)(aB + ab);                               \
        }                                                                         \
        if ((q) == 0) {                                                           \
            _Pragma("unroll") for (int nt = 0; nt < NT; ++nt)                     \
            _Pragma("unroll") for (int ks = 0; ks < 2; ++ks) {                    \
                const int bb2 = (bc0 + nt * 16 + rl) * 128 +                      \
                                ((((ks << 2) + g) ^ rx) << 4);                    \
                bfr[nt][ks] = *(const bf16x8*)(bB + bb2);                         \
            }                                                                     \
        }                                                                         \
        STG;                                                                      \
        if (VM) {                                                                 \
            if (last) {                                                           \
                asm volatile("s_waitcnt vmcnt(0)" ::: "memory");                  \
            } else {                                                              \
                asm volatile("s_waitcnt vmcnt(7)" ::: "memory");                  \
            }                                                                     \
        }                                                                         \
        __builtin_amdgcn_s_barrier();                                             \
        __builtin_amdgcn_s_setprio(1);                                            \
        _Pragma("unroll") for (int ks = 0; ks < 2; ++ks)                          \
        _Pragma("unroll") for (int mi = 0; mi < 2; ++mi)                          \
        _Pragma("unroll") for (int nt = 0; nt < NT; ++nt)                         \
            acc[q][mi][nt] = mfma16(af[mi][ks], bfr[nt][ks], acc[q][mi][nt]);     \
        __builtin_amdgcn_s_setprio(0);                                            \
        __builtin_amdgcn_s_barrier();                                             \
    }

    STG_A(0, 0); STG_A(0, 1);
    STG_A(1, 0); STG_A(1, 1);
    STG_B(0); STG_B(1);
    __syncthreads();

    for (int i = 0; i < 32; ++i) {
        const bool last = (i == 31);
        const int e = 2 * i, o = 2 * i + 1;
        const int pe = e % 3;
        const int po = (e + 1) % 3;
        PH(pe, 0, 0, STG_A(e + 2, 0), 0)
        PH(pe, 0, 1, STG_A(e + 2, 1), 0)
        PH(pe, 0, 2, STG_B(e + 2), 0)
        PH(pe, 0, 3, ((void)0), 1)
        PH(po, 1, 0, STG_A(o + 2, 0), 0)
        PH(po, 1, 1, STG_A(o + 2, 1), 0)
        PH(po, 1, 2, STG_B(o + 2), 0)
        PH(po, 1, 3, ((void)0), 1)
    }
#undef PH
#undef STG_A
#undef STG_B

#pragma unroll
    for (int q = 0; q < 4; ++q)
#pragma unroll
        for (int mi = 0; mi < 2; ++mi)
#pragma unroll
            for (int nt = 0; nt < NT; ++nt) {
                const int row0 = m0 + wm * 128 + q * 32 + mi * 16 + g * 4;
                const int gc = n0 + bc0 + nt * 16 + rl;
                const int sel = gc >> 12;          // 0:Q 1:K 2:V
                const int col = gc & 4095;
                if (sel == 2) {
                    ushort4_t v;
#pragma unroll
                    for (int r = 0; r < 4; ++r) v[r] = f2bf(acc[q][mi][nt][r]);
                    *(ushort4_t*)&Ovt[(size_t)col * S + row0] = v;
                } else {
                    unsigned short* op = sel ? Ok : Oq;
#pragma unroll
                    for (int r = 0; r < 4; ++r)
                        op[(size_t)(row0 + r) * 4096 + col] = f2bf(acc[q][mi][nt][r]);
                }
            }
}

// ---------------- 8-phase 256x128 GEMM (R8-validated) for O-projection ------
__global__ __launch_bounds__(512, 2) void gemm_out8(const unsigned short* __restrict__ Ap,
                                                    const unsigned short* __restrict__ Bp,
                                                    float* __restrict__ Of) {
    constexpr int BN = 128, NT = 2, NB = 2;
    extern __shared__ unsigned short lds8[];
    unsigned short (*As)[8192] = (unsigned short(*)[8192])lds8;
    unsigned short* Bs0 = lds8 + 4 * 8192;
    unsigned short* Bs1 = Bs0 + BN * 64;

    const int tix = threadIdx.x;
    const int lane = tix & 63;
    const int w = tix >> 6;
    const int g = lane >> 4;
    const int rl = lane & 15;
    const int wm = w >> 2;
    const int wn = w & 3;
    const int bc0 = wn * (BN / 4);
    const int rx = rl & 7;

    const int yy = blockIdx.x & 7;
    const int xx = blockIdx.x >> 3;
    const int m0 = yy * 256;
    const int n0 = xx * BN;

    int srowA[2], scolA[2];
#pragma unroll
    for (int u = 0; u < 2; ++u) {
        const int c = u * 512 + tix;
        srowA[u] = c >> 3;
        scolA[u] = ((c & 7) ^ (srowA[u] & 7)) << 3;
    }
    int srowB[NB], scolB[NB];
#pragma unroll
    for (int u = 0; u < NB; ++u) {
        const int c = u * 512 + tix;
        srowB[u] = c >> 3;
        scolB[u] = ((c & 7) ^ (srowB[u] & 7)) << 3;
    }

    const char* aBase[2] = {(const char*)As[wm], (const char*)As[2 + wm]};
    const char* bBase[2] = {(const char*)Bs0, (const char*)Bs1};

    f32x4 acc[4][2][NT] = {};
    bf16x8 bfr[NT][2];

#define STG_A8(t, h, slot)                                                        \
    if ((t) < 64) {                                                               \
        _Pragma("unroll") for (int u = 0; u < 2; ++u)                             \
            gload_lds16(Ap + (size_t)(m0 + (h) * 128 + srowA[u]) * 4096 +         \
                            (t) * 64 + scolA[u],                                  \
                        &As[slot][(u * 512 + tix) * 8]);                          \
    }
#define STG_B8(t, slot)                                                           \
    if ((t) < 64) {                                                               \
        unsigned short* bs_ = (slot) ? Bs1 : Bs0;                                 \
        _Pragma("unroll") for (int u = 0; u < NB; ++u)                            \
            gload_lds16(Bp + (size_t)(n0 + srowB[u]) * 4096 +                     \
                            (t) * 64 + scolB[u],                                  \
                        &bs_[(u * 512 + tix) * 8]);                               \
    }

#define PHASE8(pt, q, STG, VM)                                                    \
    {                                                                             \
        bf16x8 af[2][2];                                                          \
        _Pragma("unroll") for (int mi = 0; mi < 2; ++mi)                          \
        _Pragma("unroll") for (int ks = 0; ks < 2; ++ks) {                        \
            const int ab = ((q) * 32 + mi * 16 + rl) * 128 +                      \
                           ((((ks << 2) + g) ^ rx) << 4);                         \
            af[mi][ks] = *(const bf16x8*)(aBase[pt] + ab);                        \
        }                                                                         \
        if ((q) == 0) {                                                           \
            _Pragma("unroll") for (int nt = 0; nt < NT; ++nt)                     \
            _Pragma("unroll") for (int ks = 0; ks < 2; ++ks) {                    \
                const int bb = (bc0 + nt * 16 + rl) * 128 +                       \
                               ((((ks << 2) + g) ^ rx) << 4);                     \
                bfr[nt][ks] = *(const bf16x8*)(bBase[pt] + bb);                   \
            }                                                                     \
        }                                                                         \
        STG;                                                                      \
        if (VM) {                                                                 \
            if (last) {                                                           \
                asm volatile("s_waitcnt vmcnt(0)" ::: "memory");                  \
            } else {                                                              \
                asm volatile("s_waitcnt vmcnt(2)" ::: "memory");                  \
            }                                                                     \
        }                                                                         \
        __builtin_amdgcn_s_barrier();                                             \
        __builtin_amdgcn_s_setprio(1);                                            \
        _Pragma("unroll") for (int ks = 0; ks < 2; ++ks)                          \
        _Pragma("unroll") for (int mi = 0; mi < 2; ++mi)                          \
        _Pragma("unroll") for (int nt = 0; nt < NT; ++nt)                         \
            acc[q][mi][nt] = mfma16(af[mi][ks], bfr[nt][ks], acc[q][mi][nt]);     \
        __builtin_amdgcn_s_setprio(0);                                            \
        __builtin_amdgcn_s_barrier();                                             \
    }

    STG_A8(0, 0, 0); STG_A8(0, 1, 1);
    STG_B8(0, 0); STG_B8(1, 1);
    __syncthreads();

    for (int i = 0; i < 32; ++i) {
        const bool last = (i == 31);
        const int o = 2 * i + 1, ne = 2 * i + 2, no = 2 * i + 3;
        PHASE8(0, 0, STG_A8(o, 0, 2), 0)
        PHASE8(0, 1, STG_A8(o, 1, 3), 0)
        PHASE8(0, 2, STG_B8(ne, 0), 0)
        PHASE8(0, 3, ((void)0), 1)
        PHASE8(1, 0, STG_A8(ne, 0, 0), 0)
        PHASE8(1, 1, STG_A8(ne, 1, 1), 0)
        PHASE8(1, 2, STG_B8(no, 1), 0)
        PHASE8(1, 3, ((void)0), 1)
    }
#undef PHASE8
#undef STG_A8
#undef STG_B8

#pragma unroll
    for (int q = 0; q < 4; ++q)
#pragma unroll
        for (int mi = 0; mi < 2; ++mi)
#pragma unroll
            for (int nt = 0; nt < NT; ++nt) {
                const int row0 = m0 + wm * 128 + q * 32 + mi * 16 + g * 4;
                const int gc = n0 + bc0 + nt * 16 + rl;
#pragma unroll
                for (int r = 0; r < 4; ++r)
                    Of[(size_t)(row0 + r) * 4096 + gc] = acc[q][mi][nt][r];
            }
}

// ---------------- RoPE in place on Q and K ([S][D] bf16) --------------------
__global__ __launch_bounds__(256) void rope_kernel(unsigned short* __restrict__ Qb,
                                                   unsigned short* __restrict__ Kb,
                                                   const float* __restrict__ cosT,
                                                   const float* __restrict__ sinT) {
    const int i = blockIdx.x * 256 + threadIdx.x;
    const int j8 = i & 7;
    const int h = (i >> 3) & 31;
    const int s = i >> 8;
    const size_t base = (size_t)s * D + h * HD + j8 * 8;
    const float* cp = cosT + s * HD + j8 * 8;
    const float* sp = sinT + s * HD + j8 * 8;
    float c1[8], s1[8], c2[8], s2[8];
#pragma unroll
    for (int k = 0; k < 8; ++k) { c1[k] = cp[k]; s1[k] = sp[k]; c2[k] = cp[k + 64]; s2[k] = sp[k + 64]; }

#pragma unroll
    for (int w = 0; w < 2; ++w) {
        unsigned short* p = (w == 0 ? Qb : Kb) + base;
        const float f = (w == 0) ? kSc : 1.0f;
        ushort8_t x1 = *(ushort8_t*)p;
        ushort8_t x2 = *(ushort8_t*)(p + 64);
        ushort8_t o1, o2;
#pragma unroll
        for (int k = 0; k < 8; ++k) {
            const float a = bf2f(x1[k]);
            const float b = bf2f(x2[k]);
            o1[k] = f2bf((a * c1[k] - b * s1[k]) * f);
            o2[k] = f2bf((b * c2[k] + a * s2[k]) * f);
        }
        *(ushort8_t*)p = o1;
        *(ushort8_t*)(p + 64) = o2;
    }
}

// ---------------- causal flash attention: paired 64-row q-tiles -------------
// 256 thr = 4 waves. Waves 0-1 own q-tile th=16+pp (64 rows), waves 2-3 own
// tl=15-pp: per block exactly 33 active-wave-iters (balanced), and 64KB LDS
// -> 2 INDEPENDENT blocks/CU so softmax VALU, staging drains and barriers of
// one block overlap the other's MFMA (m114). Inner algorithm identical to the
// R9-validated version (swapped-operand MFMA, in-reg softmax, defer-max).
// Grid = 16 pairs x 32 heads = 512 blocks = exactly 2/CU.
__global__ __launch_bounds__(256, 2) void flash_attn(const unsigned short* __restrict__ Q,
                                                     const unsigned short* __restrict__ K,
                                                     const unsigned short* __restrict__ V,
                                                     unsigned short* __restrict__ O) {
    extern __shared__ unsigned short ldsA[];
    // Ks dbuf: 2 x 8192 elems @0; Vs: 8192 @16384; P: 4 x 2048 @24576. 64KB.

    const int t = threadIdx.x;
    const int lane = t & 63;
    const int wid = t >> 6;               // 0..3
    const int g = lane >> 4;
    const int rl = lane & 15;
    const int bid = blockIdx.x;
    const int pp = 15 - (bid >> 5);       // heavy pairs first
    const int h = bid & 31;
    const int qt = (wid < 2) ? (16 + pp) : (15 - pp);  // 64-row q-tile
    const int wrow0 = qt * 64 + (wid & 1) * 32;

    bf16x8 qf[2][4];
#pragma unroll
    for (int mi = 0; mi < 2; ++mi) {
        const unsigned short* qp = Q + (size_t)(wrow0 + mi * 16 + rl) * D + h * HD;
#pragma unroll
        for (int ks = 0; ks < 4; ++ks) qf[mi][ks] = *(const bf16x8*)(qp + ks * 32 + g * 8);
    }

    f32x4 accO[2][8] = {};
    float m2s[2] = {-1e30f, -1e30f};
    float lsum[2] = {0.f, 0.f};

    // prologue: stage K tile 0 into buf 0 (256 threads x 4 chunks)
#pragma unroll
    for (int r = 0; r < 4; ++r) {
        const int c = r * 256 + t;
        const int rowk = c >> 4;
        const int srck = (c & 15) ^ (rowk & 7);
        gload_lds16(K + (size_t)rowk * D + h * HD + srck * 8, &ldsA[c * 8]);
    }
    __syncthreads();

    int cur = 0;
    const int ntiles = (16 + pp) + 1;     // driven by the heavy tile
    for (int kv = 0; kv < ntiles; ++kv) {
        const int kv0 = kv * 64;
        // stage V[kv] + prefetch K[kv+1]
#pragma unroll
        for (int r = 0; r < 4; ++r) {
            const int c = r * 256 + t;
            const int rowv = c >> 3;
            const int srcv = (c & 7) ^ (rowv & 7);
            gload_lds16(V + (size_t)(h * HD + rowv) * S + kv0 + srcv * 8,
                        &ldsA[16384 + c * 8]);
        }
        if (kv + 1 < ntiles) {
#pragma unroll
            for (int r = 0; r < 4; ++r) {
                const int c = r * 256 + t;
                const int rowk = c >> 4;
                const int srck = (c & 15) ^ (rowk & 7);
                gload_lds16(K + (size_t)(kv0 + 64 + rowk) * D + h * HD + srck * 8,
                            &ldsA[(cur ^ 1) * 8192 + c * 8]);
            }
        }

        const bool active = kv0 <= wrow0 + 31;  // wave-uniform
        if (active) {
            const unsigned short* KsC = ldsA + cur * 8192;
            f32x4 sf[2][4];
#pragma unroll
            for (int mi = 0; mi < 2; ++mi)
#pragma unroll
                for (int nt = 0; nt < 4; ++nt) sf[mi][nt] = f32x4{0.f, 0.f, 0.f, 0.f};
            __builtin_amdgcn_s_setprio(1);
#pragma unroll
            for (int nt = 0; nt < 4; ++nt) {
                const int row = nt * 16 + rl;
#pragma unroll
                for (int ks = 0; ks < 4; ++ks) {
                    bf16x8 kf = *(const bf16x8*)&KsC[row * 128 + (((ks * 4 + g) ^ (row & 7)) << 3)];
                    sf[0][nt] = mfma16(kf, qf[0][ks], sf[0][nt]);
                    sf[1][nt] = mfma16(kf, qf[1][ks], sf[1][nt]);
                }
            }
            __builtin_amdgcn_s_setprio(0);

            const bool needMask = (kv0 + 63 > wrow0);
            float cf2[2];
            bool chg = false;
#pragma unroll
            for (int mi = 0; mi < 2; ++mi) {
                const int qrow = wrow0 + mi * 16 + rl;
                float mx = -1e30f;
                if (needMask) {
#pragma unroll
                    for (int nt = 0; nt < 4; ++nt)
#pragma unroll
                        for (int r = 0; r < 4; ++r) {
                            const int kcol = kv0 + nt * 16 + g * 4 + r;
                            float s = sf[mi][nt][r];
                            s = (kcol > qrow) ? -1e30f : s;
                            sf[mi][nt][r] = s;
                            mx = fmaxf(mx, s);
                        }
                } else {
#pragma unroll
                    for (int nt = 0; nt < 4; ++nt)
#pragma unroll
                        for (int r = 0; r < 4; ++r) mx = fmaxf(mx, sf[mi][nt][r]);
                }
                mx = fmaxf(mx, __shfl_xor(mx, 16));
                mx = fmaxf(mx, __shfl_xor(mx, 32));
                const float mn = (mx <= m2s[mi] + 8.f) ? m2s[mi] : mx;
                cf2[mi] = __builtin_amdgcn_exp2f(m2s[mi] - mn);
                chg |= (mn > m2s[mi]);
                m2s[mi] = mn;
                float rs = 0.f;
#pragma unroll
                for (int nt = 0; nt < 4; ++nt)
#pragma unroll
                    for (int r = 0; r < 4; ++r) {
                        const float pv = __builtin_amdgcn_exp2f(sf[mi][nt][r] - mn);
                        sf[mi][nt][r] = pv;
                        rs += pv;
                    }
                rs += __shfl_xor(rs, 16);
                rs += __shfl_xor(rs, 32);
                lsum[mi] = lsum[mi] * cf2[mi] + rs;
            }

            if (__any((int)chg)) {
#pragma unroll
                for (int mi = 0; mi < 2; ++mi)
#pragma unroll
                    for (int nt = 0; nt < 8; ++nt)
#pragma unroll
                        for (int r = 0; r < 4; ++r) accO[mi][nt][r] *= cf2[mi];
            }

            unsigned short* myP = ldsA + 24576 + wid * 2048;
#pragma unroll
            for (int mi = 0; mi < 2; ++mi) {
                const int row = mi * 16 + rl;
                const int rxp = row & 7;
#pragma unroll
                for (int nt = 0; nt < 4; ++nt) {
                    ushort4_t v;
#pragma unroll
                    for (int r = 0; r < 4; ++r) v[r] = f2bf(sf[mi][nt][r]);
                    const int chunk = nt * 2 + (g >> 1);
                    *(ushort4_t*)&myP[row * 64 + ((chunk ^ rxp) << 3) + ((g & 1) << 2)] = v;
                }
            }
        }
        __syncthreads();  // drains V + K-next staging; P visible

        if (active) {
            unsigned short* myP = ldsA + 24576 + wid * 2048;
            const unsigned short* VsC = ldsA + 16384;
            __builtin_amdgcn_s_setprio(1);
#pragma unroll
            for (int ks = 0; ks < 2; ++ks) {
                bf16x8 pa[2];
#pragma unroll
                for (int mi = 0; mi < 2; ++mi) {
                    const int row = mi * 16 + rl;
                    pa[mi] = *(const bf16x8*)&myP[row * 64 + (((ks * 4 + g) ^ (row & 7)) << 3)];
                }
#pragma unroll
                for (int nt = 0; nt < 8; ++nt) {
                    const int vrow = nt * 16 + rl;
                    bf16x8 vf = *(const bf16x8*)&VsC[vrow * 64 + (((ks * 4 + g) ^ (vrow & 7)) << 3)];
                    accO[0][nt] = mfma16(vf, pa[0], accO[0][nt]);
                    accO[1][nt] = mfma16(vf, pa[1], accO[1][nt]);
                }
            }
            __builtin_amdgcn_s_setprio(0);
        }
        __syncthreads();  // all PV reads done before next iter's stages
        cur ^= 1;
    }

#pragma unroll
    for (int mi = 0; mi < 2; ++mi) {
        const float inv = 1.0f / lsum[mi];
        const int qrow = wrow0 + mi * 16 + rl;
#pragma unroll
        for (int nt = 0; nt < 8; ++nt) {
            ushort4_t v;
#pragma unroll
            for (int r = 0; r < 4; ++r) v[r] = f2bf(accO[mi][nt][r] * inv);
            *(ushort4_t*)&O[(size_t)qrow * D + h * HD + nt * 16 + g * 4] = v;
        }
    }
}

// ---------------- launch ----------------------------------------------------
extern "C" void kernel_launch(void* const* d_in, const int* in_sizes, int n_in,
                              void* d_out, int out_size, void* d_ws, size_t ws_size,
                              hipStream_t stream) {
    const float* hs   = (const float*)d_in[0];
    const float* cosT = (const float*)d_in[2];
    const float* sinT = (const float*)d_in[3];
    const float* Wq   = (const float*)d_in[4];
    const float* Wk   = (const float*)d_in[5];
    const float* Wv   = (const float*)d_in[6];
    const float* Wo   = (const float*)d_in[7];

    char* ws = (char*)d_ws;
    const size_t MB = 1ull << 20;
    unsigned short* hsb = (unsigned short*)(ws);             // 16 MB  [S][D]
    unsigned short* wqb = (unsigned short*)(ws + 16 * MB);   // 3x32MB contiguous [12288][4096]
    unsigned short* wkb = (unsigned short*)(ws + 48 * MB);
    unsigned short* wvb = (unsigned short*)(ws + 80 * MB);
    unsigned short* wob = (unsigned short*)(ws + 112 * MB);
    unsigned short* Qb  = (unsigned short*)(ws + 144 * MB);  // 16 MB [S][D]
    unsigned short* Kb  = (unsigned short*)(ws + 160 * MB);  // 16 MB [S][D]
    unsigned short* Vt  = (unsigned short*)(ws + 176 * MB);  // 16 MB [D][S] (V^T)
    unsigned short* AOb = (unsigned short*)(ws + 192 * MB);  // 16 MB [S][D]

    cvt_all<<<4096 + 4 * 8192, 256, 0, stream>>>(hs, Wq, Wk, Wv, Wo,
                                                 hsb, wqb, wkb, wvb, wob);

    // QKV: 256x192 tiles, depth-8 A-prefetch, 144KB LDS, 512 blocks = 2 rounds.
    gemm_qkv8d<<<512, 512, 147456, stream>>>(hsb, wqb, Qb, Kb, Vt);

    rope_kernel<<<2048, 256, 0, stream>>>(Qb, Kb, cosT, sinT);

    // paired 64-row q-tiles: 16 pairs x 32 heads = 512 blocks, 64KB = 2/CU.
    flash_attn<<<512, 256, 65536, stream>>>(Qb, Kb, Vt, AOb);

    // O-proj: 256x128 tiles -> 8m x 32n = 256 blocks (R8-validated 8-phase).
    gemm_out8<<<256, 512, 98304, stream>>>(AOb, wob, (float*)d_out);
}

// Round 16
// 410.571 us; speedup vs baseline: 1.0124x; 1.0124x over previous
//
#include <hip/hip_runtime.h>
#include <hip/hip_bf16.h>
#include <stdint.h>

#define DEV __device__ __forceinline__

typedef __bf16 bf16x8 __attribute__((ext_vector_type(8)));
typedef float f32x4 __attribute__((ext_vector_type(4)));
typedef unsigned short ushort8_t __attribute__((ext_vector_type(8)));
typedef unsigned short ushort4_t __attribute__((ext_vector_type(4)));

constexpr int S = 2048;
constexpr int D = 4096;
constexpr int H = 32;
constexpr int HD = 128;
constexpr float kSc = 0.08838834764831845f * 1.4426950408889634f;  // 1/sqrt(HD) * log2(e)

DEV unsigned short f2bf(float f) {
    uint32_t u = __builtin_bit_cast(uint32_t, f);
    u += 0x7fffu + ((u >> 16) & 1u);
    return (unsigned short)(u >> 16);
}
DEV float bf2f(unsigned short h) {
    uint32_t u = ((uint32_t)h) << 16;
    return __builtin_bit_cast(float, u);
}

DEV void gload_lds16(const void* g, void* l) {
    __builtin_amdgcn_global_load_lds(
        (const __attribute__((address_space(1))) void*)g,
        (__attribute__((address_space(3))) void*)l,
        16, 0, 0);
}

DEV f32x4 mfma16(bf16x8 a, bf16x8 b, f32x4 c) {
    return __builtin_amdgcn_mfma_f32_16x16x32_bf16(a, b, c, 0, 0, 0);
}

// ---------------- fp32 -> bf16 convert, all 5 tensors in one dispatch -------
__global__ __launch_bounds__(256) void cvt_all(const float* __restrict__ hs,
                                               const float* __restrict__ w0,
                                               const float* __restrict__ w1,
                                               const float* __restrict__ w2,
                                               const float* __restrict__ w3,
                                               unsigned short* __restrict__ hsb,
                                               unsigned short* __restrict__ o0,
                                               unsigned short* __restrict__ o1,
                                               unsigned short* __restrict__ o2,
                                               unsigned short* __restrict__ o3) {
    const int b = blockIdx.x;
    const float* in;
    unsigned short* out;
    size_t blk;
    if (b < 4096) {
        in = hs; out = hsb; blk = (size_t)b;
    } else {
        const int i = b - 4096;
        const int w = i >> 13;
        const int r = i & 8191;
        in  = (w == 0) ? w0 : (w == 1) ? w1 : (w == 2) ? w2 : w3;
        out = (w == 0) ? o0 : (w == 1) ? o1 : (w == 2) ? o2 : o3;
        blk = (size_t)r;
    }
    const size_t i8 = blk * 256 + threadIdx.x;
    f32x4 a = ((const f32x4*)in)[2 * i8];
    f32x4 c = ((const f32x4*)in)[2 * i8 + 1];
    ushort8_t o;
    o[0] = f2bf(a[0]); o[1] = f2bf(a[1]); o[2] = f2bf(a[2]); o[3] = f2bf(a[3]);
    o[4] = f2bf(c[0]); o[5] = f2bf(c[1]); o[6] = f2bf(c[2]); o[7] = f2bf(c[3]);
    ((ushort8_t*)out)[i8] = o;
}

// ---------------- QKV GEMM: 256x192, 8-phase, depth-8 A-prefetch (R14) ------
__global__ __launch_bounds__(512, 2) void gemm_qkv8d(const unsigned short* __restrict__ Ap,
                                                     const unsigned short* __restrict__ Bp,
                                                     unsigned short* __restrict__ Oq,
                                                     unsigned short* __restrict__ Ok,
                                                     unsigned short* __restrict__ Ovt) {
    constexpr int NT = 3;
    extern __shared__ unsigned short lds8[];

    const int tix = threadIdx.x;
    const int lane = tix & 63;
    const int w = tix >> 6;
    const int g = lane >> 4;
    const int rl = lane & 15;
    const int wm = w >> 2;
    const int wn = w & 3;
    const int bc0 = wn * 48;
    const int rx = rl & 7;

    const int yy = blockIdx.x & 7;
    const int xx = blockIdx.x >> 3;
    const int m0 = yy * 256;
    const int n0 = xx * 192;

    int srowA[2], scolA[2];
#pragma unroll
    for (int u = 0; u < 2; ++u) {
        const int c = u * 512 + tix;
        srowA[u] = c >> 3;
        scolA[u] = ((c & 7) ^ (srowA[u] & 7)) << 3;
    }
    int srowB[3], scolB[3];
#pragma unroll
    for (int u = 0; u < 3; ++u) {
        const int c = u * 512 + tix;
        srowB[u] = c >> 3;
        scolB[u] = ((c & 7) ^ (srowB[u] & 7)) << 3;
    }

    f32x4 acc[4][2][NT] = {};
    bf16x8 bfr[NT][2];

#define STG_A(t, h)                                                               \
    if ((t) < 64) {                                                               \
        unsigned short* as_ = lds8 + (((t) % 3) * 2 + (h)) * 8192;                \
        _Pragma("unroll") for (int u = 0; u < 2; ++u)                             \
            gload_lds16(Ap + (size_t)(m0 + (h) * 128 + srowA[u]) * 4096 +         \
                            (t) * 64 + scolA[u],                                  \
                        &as_[(u * 512 + tix) * 8]);                               \
    }
#define STG_B(t)                                                                  \
    if ((t) < 64) {                                                               \
        unsigned short* bs_ = lds8 + 49152 + ((t) & 1) * 12288;                   \
        _Pragma("unroll") for (int u = 0; u < 3; ++u)                             \
            gload_lds16(Bp + (size_t)(n0 + srowB[u]) * 4096 +                     \
                            (t) * 64 + scolB[u],                                  \
                        &bs_[(u * 512 + tix) * 8]);                               \
    }

#define PH(pp, bb, q, STG, VM)                                                    \
    {                                                                             \
        const char* aB = (const char*)(lds8 + ((pp) * 2 + wm) * 8192);            \
        const char* bB = (const char*)(lds8 + 49152 + (bb) * 12288);              \
        bf16x8 af[2][2];                                                          \
        _Pragma("unroll") for (int mi = 0; mi < 2; ++mi)                          \
        _Pragma("unroll") for (int ks = 0; ks < 2; ++ks) {                        \
            const int ab = ((q) * 32 + mi * 16 + rl) * 128 +                      \
                           ((((ks << 2) + g) ^ rx) << 4);                         \
            af[mi][ks] = *(const bf16x8*)(aB + ab);                               \
        }                                                                         \
        if ((q) == 0) {                                                           \
            _Pragma("unroll") for (int nt = 0; nt < NT; ++nt)                     \
            _Pragma("unroll") for (int ks = 0; ks < 2; ++ks) {                    \
                const int bb2 = (bc0 + nt * 16 + rl) * 128 +                      \
                                ((((ks << 2) + g) ^ rx) << 4);                    \
                bfr[nt][ks] = *(const bf16x8*)(bB + bb2);                         \
            }                                                                     \
        }                                                                         \
        STG;                                                                      \
        if (VM) {                                                                 \
            if (last) {                                                           \
                asm volatile("s_waitcnt vmcnt(0)" ::: "memory");                  \
            } else {                                                              \
                asm volatile("s_waitcnt vmcnt(7)" ::: "memory");                  \
            }                                                                     \
        }                                                                         \
        __builtin_amdgcn_s_barrier();                                             \
        __builtin_amdgcn_s_setprio(1);                                            \
        _Pragma("unroll") for (int ks = 0; ks < 2; ++ks)                          \
        _Pragma("unroll") for (int mi = 0; mi < 2; ++mi)                          \
        _Pragma("unroll") for (int nt = 0; nt < NT; ++nt)                         \
            acc[q][mi][nt] = mfma16(af[mi][ks], bfr[nt][ks], acc[q][mi][nt]);     \
        __builtin_amdgcn_s_setprio(0);                                            \
        __builtin_amdgcn_s_barrier();                                             \
    }

    STG_A(0, 0); STG_A(0, 1);
    STG_A(1, 0); STG_A(1, 1);
    STG_B(0); STG_B(1);
    __syncthreads();

    for (int i = 0; i < 32; ++i) {
        const bool last = (i == 31);
        const int e = 2 * i, o = 2 * i + 1;
        const int pe = e % 3;
        const int po = (e + 1) % 3;
        PH(pe, 0, 0, STG_A(e + 2, 0), 0)
        PH(pe, 0, 1, STG_A(e + 2, 1), 0)
        PH(pe, 0, 2, STG_B(e + 2), 0)
        PH(pe, 0, 3, ((void)0), 1)
        PH(po, 1, 0, STG_A(o + 2, 0), 0)
        PH(po, 1, 1, STG_A(o + 2, 1), 0)
        PH(po, 1, 2, STG_B(o + 2), 0)
        PH(po, 1, 3, ((void)0), 1)
    }
#undef PH
#undef STG_A
#undef STG_B

#pragma unroll
    for (int q = 0; q < 4; ++q)
#pragma unroll
        for (int mi = 0; mi < 2; ++mi)
#pragma unroll
            for (int nt = 0; nt < NT; ++nt) {
                const int row0 = m0 + wm * 128 + q * 32 + mi * 16 + g * 4;
                const int gc = n0 + bc0 + nt * 16 + rl;
                const int sel = gc >> 12;          // 0:Q 1:K 2:V
                const int col = gc & 4095;
                if (sel == 2) {
                    ushort4_t v;
#pragma unroll
                    for (int r = 0; r < 4; ++r) v[r] = f2bf(acc[q][mi][nt][r]);
                    *(ushort4_t*)&Ovt[(size_t)col * S + row0] = v;
                } else {
                    unsigned short* op = sel ? Ok : Oq;
#pragma unroll
                    for (int r = 0; r < 4; ++r)
                        op[(size_t)(row0 + r) * 4096 + col] = f2bf(acc[q][mi][nt][r]);
                }
            }
}

// ---------------- 8-phase 256x128 GEMM (R8-validated) for O-projection ------
__global__ __launch_bounds__(512, 2) void gemm_out8(const unsigned short* __restrict__ Ap,
                                                    const unsigned short* __restrict__ Bp,
                                                    float* __restrict__ Of) {
    constexpr int BN = 128, NT = 2, NB = 2;
    extern __shared__ unsigned short lds8[];
    unsigned short (*As)[8192] = (unsigned short(*)[8192])lds8;
    unsigned short* Bs0 = lds8 + 4 * 8192;
    unsigned short* Bs1 = Bs0 + BN * 64;

    const int tix = threadIdx.x;
    const int lane = tix & 63;
    const int w = tix >> 6;
    const int g = lane >> 4;
    const int rl = lane & 15;
    const int wm = w >> 2;
    const int wn = w & 3;
    const int bc0 = wn * (BN / 4);
    const int rx = rl & 7;

    const int yy = blockIdx.x & 7;
    const int xx = blockIdx.x >> 3;
    const int m0 = yy * 256;
    const int n0 = xx * BN;

    int srowA[2], scolA[2];
#pragma unroll
    for (int u = 0; u < 2; ++u) {
        const int c = u * 512 + tix;
        srowA[u] = c >> 3;
        scolA[u] = ((c & 7) ^ (srowA[u] & 7)) << 3;
    }
    int srowB[NB], scolB[NB];
#pragma unroll
    for (int u = 0; u < NB; ++u) {
        const int c = u * 512 + tix;
        srowB[u] = c >> 3;
        scolB[u] = ((c & 7) ^ (srowB[u] & 7)) << 3;
    }

    const char* aBase[2] = {(const char*)As[wm], (const char*)As[2 + wm]};
    const char* bBase[2] = {(const char*)Bs0, (const char*)Bs1};

    f32x4 acc[4][2][NT] = {};
    bf16x8 bfr[NT][2];

#define STG_A8(t, h, slot)                                                        \
    if ((t) < 64) {                                                               \
        _Pragma("unroll") for (int u = 0; u < 2; ++u)                             \
            gload_lds16(Ap + (size_t)(m0 + (h) * 128 + srowA[u]) * 4096 +         \
                            (t) * 64 + scolA[u],                                  \
                        &As[slot][(u * 512 + tix) * 8]);                          \
    }
#define STG_B8(t, slot)                                                           \
    if ((t) < 64) {                                                               \
        unsigned short* bs_ = (slot) ? Bs1 : Bs0;                                 \
        _Pragma("unroll") for (int u = 0; u < NB; ++u)                            \
            gload_lds16(Bp + (size_t)(n0 + srowB[u]) * 4096 +                     \
                            (t) * 64 + scolB[u],                                  \
                        &bs_[(u * 512 + tix) * 8]);                               \
    }

#define PHASE8(pt, q, STG, VM)                                                    \
    {                                                                             \
        bf16x8 af[2][2];                                                          \
        _Pragma("unroll") for (int mi = 0; mi < 2; ++mi)                          \
        _Pragma("unroll") for (int ks = 0; ks < 2; ++ks) {                        \
            const int ab = ((q) * 32 + mi * 16 + rl) * 128 +                      \
                           ((((ks << 2) + g) ^ rx) << 4);                         \
            af[mi][ks] = *(const bf16x8*)(aBase[pt] + ab);                        \
        }                                                                         \
        if ((q) == 0) {                                                           \
            _Pragma("unroll") for (int nt = 0; nt < NT; ++nt)                     \
            _Pragma("unroll") for (int ks = 0; ks < 2; ++ks) {                    \
                const int bb = (bc0 + nt * 16 + rl) * 128 +                       \
                               ((((ks << 2) + g) ^ rx) << 4);                     \
                bfr[nt][ks] = *(const bf16x8*)(bBase[pt] + bb);                   \
            }                                                                     \
        }                                                                         \
        STG;                                                                      \
        if (VM) {                                                                 \
            if (last) {                                                           \
                asm volatile("s_waitcnt vmcnt(0)" ::: "memory");                  \
            } else {                                                              \
                asm volatile("s_waitcnt vmcnt(2)" ::: "memory");                  \
            }                                                                     \
        }                                                                         \
        __builtin_amdgcn_s_barrier();                                             \
        __builtin_amdgcn_s_setprio(1);                                            \
        _Pragma("unroll") for (int ks = 0; ks < 2; ++ks)                          \
        _Pragma("unroll") for (int mi = 0; mi < 2; ++mi)                          \
        _Pragma("unroll") for (int nt = 0; nt < NT; ++nt)                         \
            acc[q][mi][nt] = mfma16(af[mi][ks], bfr[nt][ks], acc[q][mi][nt]);     \
        __builtin_amdgcn_s_setprio(0);                                            \
        __builtin_amdgcn_s_barrier();                                             \
    }

    STG_A8(0, 0, 0); STG_A8(0, 1, 1);
    STG_B8(0, 0); STG_B8(1, 1);
    __syncthreads();

    for (int i = 0; i < 32; ++i) {
        const bool last = (i == 31);
        const int o = 2 * i + 1, ne = 2 * i + 2, no = 2 * i + 3;
        PHASE8(0, 0, STG_A8(o, 0, 2), 0)
        PHASE8(0, 1, STG_A8(o, 1, 3), 0)
        PHASE8(0, 2, STG_B8(ne, 0), 0)
        PHASE8(0, 3, ((void)0), 1)
        PHASE8(1, 0, STG_A8(ne, 0, 0), 0)
        PHASE8(1, 1, STG_A8(ne, 1, 1), 0)
        PHASE8(1, 2, STG_B8(no, 1), 0)
        PHASE8(1, 3, ((void)0), 1)
    }
#undef PHASE8
#undef STG_A8
#undef STG_B8

#pragma unroll
    for (int q = 0; q < 4; ++q)
#pragma unroll
        for (int mi = 0; mi < 2; ++mi)
#pragma unroll
            for (int nt = 0; nt < NT; ++nt) {
                const int row0 = m0 + wm * 128 + q * 32 + mi * 16 + g * 4;
                const int gc = n0 + bc0 + nt * 16 + rl;
#pragma unroll
                for (int r = 0; r < 4; ++r)
                    Of[(size_t)(row0 + r) * 4096 + gc] = acc[q][mi][nt][r];
            }
}

// ---------------- RoPE in place on Q and K ([S][D] bf16) --------------------
__global__ __launch_bounds__(256) void rope_kernel(unsigned short* __restrict__ Qb,
                                                   unsigned short* __restrict__ Kb,
                                                   const float* __restrict__ cosT,
                                                   const float* __restrict__ sinT) {
    const int i = blockIdx.x * 256 + threadIdx.x;
    const int j8 = i & 7;
    const int h = (i >> 3) & 31;
    const int s = i >> 8;
    const size_t base = (size_t)s * D + h * HD + j8 * 8;
    const float* cp = cosT + s * HD + j8 * 8;
    const float* sp = sinT + s * HD + j8 * 8;
    float c1[8], s1[8], c2[8], s2[8];
#pragma unroll
    for (int k = 0; k < 8; ++k) { c1[k] = cp[k]; s1[k] = sp[k]; c2[k] = cp[k + 64]; s2[k] = sp[k + 64]; }

#pragma unroll
    for (int w = 0; w < 2; ++w) {
        unsigned short* p = (w == 0 ? Qb : Kb) + base;
        const float f = (w == 0) ? kSc : 1.0f;
        ushort8_t x1 = *(ushort8_t*)p;
        ushort8_t x2 = *(ushort8_t*)(p + 64);
        ushort8_t o1, o2;
#pragma unroll
        for (int k = 0; k < 8; ++k) {
            const float a = bf2f(x1[k]);
            const float b = bf2f(x2[k]);
            o1[k] = f2bf((a * c1[k] - b * s1[k]) * f);
            o2[k] = f2bf((b * c2[k] + a * s2[k]) * f);
        }
        *(ushort8_t*)p = o1;
        *(ushort8_t*)(p + 64) = o2;
    }
}

// ---------------- causal flash attention: paired q-tiles (R9-validated) -----
__global__ __launch_bounds__(512, 2) void flash_attn(const unsigned short* __restrict__ Q,
                                                     const unsigned short* __restrict__ K,
                                                     const unsigned short* __restrict__ V,
                                                     unsigned short* __restrict__ O) {
    extern __shared__ unsigned short ldsA[];

    const int t = threadIdx.x;
    const int lane = t & 63;
    const int wid = t >> 6;
    const int g = lane >> 4;
    const int rl = lane & 15;
    const int bid = blockIdx.x;
    const int p = 7 - (bid >> 5);
    const int h = bid & 31;
    const int qt = (wid < 4) ? (8 + p) : (7 - p);
    const int wrow0 = qt * 128 + (wid & 3) * 32;

    bf16x8 qf[2][4];
#pragma unroll
    for (int mi = 0; mi < 2; ++mi) {
        const unsigned short* qp = Q + (size_t)(wrow0 + mi * 16 + rl) * D + h * HD;
#pragma unroll
        for (int ks = 0; ks < 4; ++ks) qf[mi][ks] = *(const bf16x8*)(qp + ks * 32 + g * 8);
    }

    f32x4 accO[2][8] = {};
    float m2s[2] = {-1e30f, -1e30f};
    float lsum[2] = {0.f, 0.f};

#pragma unroll
    for (int r = 0; r < 2; ++r) {
        const int c = r * 512 + t;
        const int rowk = c >> 4;
        const int srck = (c & 15) ^ (rowk & 7);
        gload_lds16(K + (size_t)rowk * D + h * HD + srck * 8, &ldsA[c * 8]);
    }
    __syncthreads();

    int cur = 0;
    const int ntiles = 2 * (8 + p) + 2;
    for (int kv = 0; kv < ntiles; ++kv) {
        const int kv0 = kv * 64;
#pragma unroll
        for (int r = 0; r < 2; ++r) {
            const int c = r * 512 + t;
            const int rowv = c >> 3;
            const int srcv = (c & 7) ^ (rowv & 7);
            gload_lds16(V + (size_t)(h * HD + rowv) * S + kv0 + srcv * 8,
                        &ldsA[16384 + c * 8]);
        }
        if (kv + 1 < ntiles) {
#pragma unroll
            for (int r = 0; r < 2; ++r) {
                const int c = r * 512 + t;
                const int rowk = c >> 4;
                const int srck = (c & 15) ^ (rowk & 7);
                gload_lds16(K + (size_t)(kv0 + 64 + rowk) * D + h * HD + srck * 8,
                            &ldsA[(cur ^ 1) * 8192 + c * 8]);
            }
        }

        const bool active = kv0 <= wrow0 + 31;
        if (active) {
            const unsigned short* KsC = ldsA + cur * 8192;
            f32x4 sf[2][4];
#pragma unroll
            for (int mi = 0; mi < 2; ++mi)
#pragma unroll
                for (int nt = 0; nt < 4; ++nt) sf[mi][nt] = f32x4{0.f, 0.f, 0.f, 0.f};
            __builtin_amdgcn_s_setprio(1);
#pragma unroll
            for (int nt = 0; nt < 4; ++nt) {
                const int row = nt * 16 + rl;
#pragma unroll
                for (int ks = 0; ks < 4; ++ks) {
                    bf16x8 kf = *(const bf16x8*)&KsC[row * 128 + (((ks * 4 + g) ^ (row & 7)) << 3)];
                    sf[0][nt] = mfma16(kf, qf[0][ks], sf[0][nt]);
                    sf[1][nt] = mfma16(kf, qf[1][ks], sf[1][nt]);
                }
            }
            __builtin_amdgcn_s_setprio(0);

            const bool needMask = (kv0 + 63 > wrow0);
            float cf2[2];
            bool chg = false;
#pragma unroll
            for (int mi = 0; mi < 2; ++mi) {
                const int qrow = wrow0 + mi * 16 + rl;
                float mx = -1e30f;
                if (needMask) {
#pragma unroll
                    for (int nt = 0; nt < 4; ++nt)
#pragma unroll
                        for (int r = 0; r < 4; ++r) {
                            const int kcol = kv0 + nt * 16 + g * 4 + r;
                            float s = sf[mi][nt][r];
                            s = (kcol > qrow) ? -1e30f : s;
                            sf[mi][nt][r] = s;
                            mx = fmaxf(mx, s);
                        }
                } else {
#pragma unroll
                    for (int nt = 0; nt < 4; ++nt)
#pragma unroll
                        for (int r = 0; r < 4; ++r) mx = fmaxf(mx, sf[mi][nt][r]);
                }
                mx = fmaxf(mx, __shfl_xor(mx, 16));
                mx = fmaxf(mx, __shfl_xor(mx, 32));
                const float mn = (mx <= m2s[mi] + 8.f) ? m2s[mi] : mx;
                cf2[mi] = __builtin_amdgcn_exp2f(m2s[mi] - mn);
                chg |= (mn > m2s[mi]);
                m2s[mi] = mn;
                float rs = 0.f;
#pragma unroll
                for (int nt = 0; nt < 4; ++nt)
#pragma unroll
                    for (int r = 0; r < 4; ++r) {
                        const float pv = __builtin_amdgcn_exp2f(sf[mi][nt][r] - mn);
                        sf[mi][nt][r] = pv;
                        rs += pv;
                    }
                rs += __shfl_xor(rs, 16);
                rs += __shfl_xor(rs, 32);
                lsum[mi] = lsum[mi] * cf2[mi] + rs;
            }

            if (__any((int)chg)) {
#pragma unroll
                for (int mi = 0; mi < 2; ++mi)
#pragma unroll
                    for (int nt = 0; nt < 8; ++nt)
#pragma unroll
                        for (int r = 0; r < 4; ++r) accO[mi][nt][r] *= cf2[mi];
            }

            unsigned short* myP = ldsA + 24576 + wid * 2048;
#pragma unroll
            for (int mi = 0; mi < 2; ++mi) {
                const int row = mi * 16 + rl;
                const int rxp = row & 7;
#pragma unroll
                for (int nt = 0; nt < 4; ++nt) {
                    ushort4_t v;
#pragma unroll
                    for (int r = 0; r < 4; ++r) v[r] = f2bf(sf[mi][nt][r]);
                    const int chunk = nt * 2 + (g >> 1);
                    *(ushort4_t*)&myP[row * 64 + ((chunk ^ rxp) << 3) + ((g & 1) << 2)] = v;
                }
            }
        }
        __syncthreads();

        if (active) {
            unsigned short* myP = ldsA + 24576 + wid * 2048;
            const unsigned short* VsC = ldsA + 16384;
            __builtin_amdgcn_s_setprio(1);
#pragma unroll
            for (int ks = 0; ks < 2; ++ks) {
                bf16x8 pa[2];
#pragma unroll
                for (int mi = 0; mi < 2; ++mi) {
                    const int row = mi * 16 + rl;
                    pa[mi] = *(const bf16x8*)&myP[row * 64 + (((ks * 4 + g) ^ (row & 7)) << 3)];
                }
#pragma unroll
                for (int nt = 0; nt < 8; ++nt) {
                    const int vrow = nt * 16 + rl;
                    bf16x8 vf = *(const bf16x8*)&VsC[vrow * 64 + (((ks * 4 + g) ^ (vrow & 7)) << 3)];
                    accO[0][nt] = mfma16(vf, pa[0], accO[0][nt]);
                    accO[1][nt] = mfma16(vf, pa[1], accO[1][nt]);
                }
            }
            __builtin_amdgcn_s_setprio(0);
        }
        __syncthreads();
        cur ^= 1;
    }

#pragma unroll
    for (int mi = 0; mi < 2; ++mi) {
        const float inv = 1.0f / lsum[mi];
        const int qrow = wrow0 + mi * 16 + rl;
#pragma unroll
        for (int nt = 0; nt < 8; ++nt) {
            ushort4_t v;
#pragma unroll
            for (int r = 0; r < 4; ++r) v[r] = f2bf(accO[mi][nt][r] * inv);
            *(ushort4_t*)&O[(size_t)qrow * D + h * HD + nt * 16 + g * 4] = v;
        }
    }
}

// ---------------- launch ----------------------------------------------------
extern "C" void kernel_launch(void* const* d_in, const int* in_sizes, int n_in,
                              void* d_out, int out_size, void* d_ws, size_t ws_size,
                              hipStream_t stream) {
    const float* hs   = (const float*)d_in[0];
    const float* cosT = (const float*)d_in[2];
    const float* sinT = (const float*)d_in[3];
    const float* Wq   = (const float*)d_in[4];
    const float* Wk   = (const float*)d_in[5];
    const float* Wv   = (const float*)d_in[6];
    const float* Wo   = (const float*)d_in[7];

    char* ws = (char*)d_ws;
    const size_t MB = 1ull << 20;
    unsigned short* hsb = (unsigned short*)(ws);             // 16 MB  [S][D]
    unsigned short* wqb = (unsigned short*)(ws + 16 * MB);   // 3x32MB contiguous [12288][4096]
    unsigned short* wkb = (unsigned short*)(ws + 48 * MB);
    unsigned short* wvb = (unsigned short*)(ws + 80 * MB);
    unsigned short* wob = (unsigned short*)(ws + 112 * MB);
    unsigned short* Qb  = (unsigned short*)(ws + 144 * MB);  // 16 MB [S][D]
    unsigned short* Kb  = (unsigned short*)(ws + 160 * MB);  // 16 MB [S][D]
    unsigned short* Vt  = (unsigned short*)(ws + 176 * MB);  // 16 MB [D][S] (V^T)
    unsigned short* AOb = (unsigned short*)(ws + 192 * MB);  // 16 MB [S][D]

    cvt_all<<<4096 + 4 * 8192, 256, 0, stream>>>(hs, Wq, Wk, Wv, Wo,
                                                 hsb, wqb, wkb, wvb, wob);

    // QKV: 256x192 tiles, depth-8 A-prefetch, 144KB LDS, 512 blocks = 2 rounds.
    gemm_qkv8d<<<512, 512, 147456, stream>>>(hsb, wqb, Qb, Kb, Vt);

    rope_kernel<<<2048, 256, 0, stream>>>(Qb, Kb, cosT, sinT);

    // paired q-tiles: 8 pairs x 32 heads = 256 blocks, 512 threads, 80KB LDS.
    flash_attn<<<256, 512, 81920, stream>>>(Qb, Kb, Vt, AOb);

    // O-proj: 256x128 tiles -> 8m x 32n = 256 blocks (R8-validated 8-phase).
    gemm_out8<<<256, 512, 98304, stream>>>(AOb, wob, (float*)d_out);
}